// Round 4
// baseline (9238.525 us; speedup 1.0000x reference)
//
#include <hip/hip_runtime.h>
#include <hip/hip_bf16.h>

typedef __bf16 bf16_t;
typedef __bf16 bf16x8 __attribute__((ext_vector_type(8)));
typedef float  f32x4  __attribute__((ext_vector_type(4)));
typedef float  f32x2  __attribute__((ext_vector_type(2)));

#define Bx 128
#define Sx 128
#define Tx 128
#define Ex 256
#define Hx 512
#define H2 1024
#define G3 1536
#define KX 1280   // E + 2H  (GRU input width)
#define KP 1792   // E + H + 2H (preout width)

// ---- output section offsets (elements, fp32) ----
#define OUT_STATES 0
#define OUT_HID    8388608   // B*T*H
#define OUT_PRE    8454144   // + B*H
#define OUT_CELL   16842752  // + B*T*H

__device__ __forceinline__ float fast_tanh(float x){
  float e = __expf(2.0f*x);
  return 1.0f - 2.0f/(e + 1.0f);   // safe at +/-inf
}
__device__ __forceinline__ float fast_sigmoid(float x){
  return 1.0f/(1.0f + __expf(-x));
}

// load 8 contiguous fp32 and round to bf16x8 (RNE via HW cvt)
__device__ __forceinline__ bf16x8 ld_cvt8(const float* p){
  f32x4 a = *(const f32x4*)p;
  f32x4 b = *(const f32x4*)(p+4);
  bf16x8 r;
  r[0]=(bf16_t)a[0]; r[1]=(bf16_t)a[1]; r[2]=(bf16_t)a[2]; r[3]=(bf16_t)a[3];
  r[4]=(bf16_t)b[0]; r[5]=(bf16_t)b[1]; r[6]=(bf16_t)b[2]; r[7]=(bf16_t)b[3];
  return r;
}

// NT GEMM tile (both operands already bf16): C[16,16] += A[16,K] * W[16,K]^T
// gfx950 layouts: A/B frag: row=lane&15, k=(lane>>4)*8+j ; D: row=(lane>>4)*4+r, col=lane&15
__device__ __forceinline__ f32x4 gemm_tile_bb(const bf16_t* A, int lda,
                                              const bf16_t* W, int ldw, int K, int lane){
  const int quad = lane >> 4, c = lane & 15;
  const bf16_t* pa = A + c*lda + quad*8;
  const bf16_t* pb = W + c*ldw + quad*8;
  f32x4 acc = {0.f,0.f,0.f,0.f};
  for (int k = 0; k < K; k += 32)
    acc = __builtin_amdgcn_mfma_f32_16x16x32_bf16(*(const bf16x8*)(pa+k),
                                                  *(const bf16x8*)(pb+k), acc, 0, 0, 0);
  return acc;
}

__device__ __forceinline__ void store_tile_f32(float* C, int ldc, f32x4 acc, int lane){
  const int quad = lane >> 4, c = lane & 15;
  #pragma unroll
  for (int r = 0; r < 4; r++) C[(quad*4 + r)*ldc + c] = acc[r];
}

// ---------------- fp32 -> bf16 convert (n % 4 == 0) ------------------------------------
__global__ void cvt_kernel(const float* __restrict__ in, bf16_t* __restrict__ out, int n){
  const int i = (blockIdx.x*256 + threadIdx.x)*4;
  if (i < n){
    f32x4 v = *(const f32x4*)(in + i);
    bf16_t o[4]; o[0]=(bf16_t)v[0]; o[1]=(bf16_t)v[1]; o[2]=(bf16_t)v[2]; o[3]=(bf16_t)v[3];
    *(ulong1*)(out + i) = *(ulong1*)o;
  }
}

// ---------------- bridge: h0 = tanh(encoder_final @ W_bridge^T + b_bridge) -------------
__global__ void bridge_kernel(const float* __restrict__ ef, const float* __restrict__ Wb,
                              const float* __restrict__ bb,
                              float* __restrict__ hf, bf16_t* __restrict__ hb){
  const int b = blockIdx.x;        // 128
  const int h = threadIdx.x;       // 512
  __shared__ float efs[H2];
  for (int k = threadIdx.x; k < H2; k += blockDim.x) efs[k] = ef[b*H2 + k];
  __syncthreads();
  const float* wrow = Wb + h*H2;
  float acc = bb[h];
  for (int k = 0; k < H2; k += 4){
    f32x4 w = *(const f32x4*)(wrow + k);
    acc += efs[k]*w[0] + efs[k+1]*w[1] + efs[k+2]*w[2] + efs[k+3]*w[3];
  }
  float v = fast_tanh(acc);
  hf[b*Hx + h] = v;
  hb[b*Hx + h] = (bf16_t)v;
}

// ---------------- proj_key = encoder_hidden @ W_key^T  (16384x512, K=1024) -------------
// A = eh (fp32, converted on the fly), B = Wk_bf16
__global__ void pk_gemm(const float* __restrict__ eh, const bf16_t* __restrict__ Wkb,
                        bf16_t* __restrict__ pk){
  const int gwid = (blockIdx.x*blockDim.x + threadIdx.x) >> 6;  // 0..32767
  const int lane = threadIdx.x & 63;
  const int quad = lane >> 4, c = lane & 15;
  const int mt = gwid >> 5;   // 1024 m-tiles
  const int nt = gwid & 31;   // 32 n-tiles
  const float*  pa = eh  + (mt*16 + c)*H2 + quad*8;
  const bf16_t* pb = Wkb + (nt*16 + c)*H2 + quad*8;
  f32x4 acc = {0.f,0.f,0.f,0.f};
  for (int k = 0; k < H2; k += 32)
    acc = __builtin_amdgcn_mfma_f32_16x16x32_bf16(ld_cvt8(pa + k),
                                                  *(const bf16x8*)(pb + k), acc, 0,0,0);
  bf16_t* C = pk + mt*16*Hx + nt*16;
  #pragma unroll
  for (int r = 0; r < 4; r++) C[(quad*4 + r)*Hx + c] = (bf16_t)acc[r];
}

// ---------------- P1: q = h@Wq^T, gh = h@Whh^T (per step) ------------------------------
__global__ void __launch_bounds__(256)
p1_kernel(const bf16_t* __restrict__ hb, const bf16_t* __restrict__ Wqb,
          const bf16_t* __restrict__ Whhb, float* __restrict__ qf, float* __restrict__ ghf){
  const int lane = threadIdx.x & 63;
  const int gw = blockIdx.x*4 + (threadIdx.x >> 6);   // 0..1023
  if (gw < 256){
    const int mt = gw >> 5, nt = gw & 31;
    f32x4 acc = gemm_tile_bb(hb + mt*16*Hx, Hx, Wqb + nt*16*Hx, Hx, Hx, lane);
    store_tile_f32(qf + mt*16*Hx + nt*16, Hx, acc, lane);
  } else {
    const int idx = gw - 256;              // 0..767
    const int mt = idx/96, nt = idx%96;
    f32x4 acc = gemm_tile_bb(hb + mt*16*Hx, Hx, Whhb + nt*16*Hx, Hx, Hx, lane);
    store_tile_f32(ghf + mt*16*G3 + nt*16, G3, acc, lane);
  }
}

// ---------------- P2: scores -> softmax -> context (per step; block=(b,half)) ----------
__global__ void __launch_bounds__(256)
p2_kernel(const float* __restrict__ trg, const float* __restrict__ eh,
          const float* __restrict__ ven, const bf16_t* __restrict__ pk,
          const float* __restrict__ qf, bf16_t* __restrict__ xbuf, int t){
  const int tid  = threadIdx.x;
  const int lane = tid & 63;
  const int wid  = tid >> 6;
  const int b    = blockIdx.x >> 1;
  const int half = blockIdx.x & 1;

  __shared__ float sc[Sx];
  __shared__ float smax_s, ssum_s;

  float qv[8], vv[8];
  #pragma unroll
  for (int i = 0; i < 8; i++){
    qv[i] = qf[b*Hx + i*64 + lane];
    vv[i] = ven[i*64 + lane];
  }
  for (int j = 0; j < 32; j++){
    const int s = wid*32 + j;
    const bf16_t* row = pk + (b*Sx + s)*Hx;
    float p = 0.f;
    #pragma unroll
    for (int i = 0; i < 8; i++)
      p += fast_tanh(qv[i] + (float)row[i*64 + lane])*vv[i];
    #pragma unroll
    for (int o = 32; o; o >>= 1) p += __shfl_xor(p, o, 64);
    if (lane == 0) sc[s] = p;
  }
  __syncthreads();
  if (tid < 64){
    float m = fmaxf(sc[tid], sc[tid+64]);
    #pragma unroll
    for (int o = 32; o; o >>= 1) m = fmaxf(m, __shfl_xor(m, o, 64));
    if (tid == 0) smax_s = m;
  }
  __syncthreads();
  if (tid < 128) sc[tid] = __expf(sc[tid] - smax_s);
  __syncthreads();
  if (tid < 64){
    float ssum = sc[tid] + sc[tid+64];
    #pragma unroll
    for (int o = 32; o; o >>= 1) ssum += __shfl_xor(ssum, o, 64);
    if (tid == 0) ssum_s = ssum;
  }
  __syncthreads();
  const float inv = 1.0f/ssum_s;
  const int d0 = half*Hx + tid*2;
  const float* ehb = eh + b*Sx*H2;
  float c0 = 0.f, c1 = 0.f;
  #pragma unroll 4
  for (int s = 0; s < Sx; s++){
    const float a = sc[s];
    f32x2 v = *(const f32x2*)(ehb + s*H2 + d0);
    c0 += a*v[0];
    c1 += a*v[1];
  }
  c0 *= inv; c1 *= inv;
  bf16_t cb[2]; cb[0] = (bf16_t)c0; cb[1] = (bf16_t)c1;
  *(uint1*)(xbuf + b*KX + Ex + d0) = *(uint1*)cb;
  if (half == 0) xbuf[b*KX + tid] = (bf16_t)trg[(b*Tx + t)*Ex + tid];
}

// ---------------- P3: gi GEMM + GRU combine; preout-ctx partial (per step) -------------
__global__ void __launch_bounds__(256)
p3_kernel(const bf16_t* __restrict__ Wihb, const float* __restrict__ bih,
          const float* __restrict__ bhh, const bf16_t* __restrict__ Wpb,
          const bf16_t* __restrict__ xbuf, const float* __restrict__ ghf,
          float* __restrict__ hf, bf16_t* __restrict__ hb,
          float* __restrict__ states, float* __restrict__ pre, int t){
  const int lane = threadIdx.x & 63;
  const int gw = blockIdx.x*4 + (threadIdx.x >> 6);   // 0..511 (128 blocks)
  const int quad = lane >> 4, c16 = lane & 15;

  if (gw < 256){
    const int mt = gw >> 5, ntp = gw & 31;
    const bf16_t* A  = xbuf + (mt*16 + c16)*KX + quad*8;
    const bf16_t* B0 = Wihb + (ntp*16 + c16)*KX + quad*8;
    const bf16_t* B1 = B0 + Hx*KX;
    const bf16_t* B2 = B0 + H2*KX;
    f32x4 ar = {0.f,0.f,0.f,0.f}, az = ar, an = ar;
    for (int k = 0; k < KX; k += 32){
      bf16x8 a = *(const bf16x8*)(A + k);
      ar = __builtin_amdgcn_mfma_f32_16x16x32_bf16(a, *(const bf16x8*)(B0+k), ar, 0,0,0);
      az = __builtin_amdgcn_mfma_f32_16x16x32_bf16(a, *(const bf16x8*)(B1+k), az, 0,0,0);
      an = __builtin_amdgcn_mfma_f32_16x16x32_bf16(a, *(const bf16x8*)(B2+k), an, 0,0,0);
    }
    const int j = ntp*16 + c16;
    const float bir = bih[j], biz = bih[Hx+j], bin = bih[H2+j];
    const float bhr = bhh[j], bhz = bhh[Hx+j], bhn = bhh[H2+j];
    #pragma unroll
    for (int r = 0; r < 4; r++){
      const int b_ = mt*16 + quad*4 + r;
      const float hr = ghf[b_*G3 + j]       + bhr;
      const float hz = ghf[b_*G3 + Hx + j]  + bhz;
      const float hn = ghf[b_*G3 + H2 + j]  + bhn;
      const float rg = fast_sigmoid(ar[r] + bir + hr);
      const float zg = fast_sigmoid(az[r] + biz + hz);
      const float ng = fast_tanh(an[r] + bin + rg*hn);
      const float hold = hf[b_*Hx + j];
      const float hnew = (1.0f - zg)*ng + zg*hold;
      hf[b_*Hx + j] = hnew;
      hb[b_*Hx + j] = (bf16_t)hnew;
      states[(b_*Tx + t)*Hx + j] = hnew;
    }
  } else {
    // pre_ctx = ctx @ Wp[:,768:1792]^T  -> pre (ctx partial, fp32)
    const int idx = gw - 256;
    const int mt2 = idx >> 5, nt2 = idx & 31;
    const bf16_t* A = xbuf + (mt2*16 + c16)*KX + Ex + quad*8;
    const bf16_t* B = Wpb + (nt2*16 + c16)*KP + (Ex + Hx) + quad*8;
    f32x4 acc = {0.f,0.f,0.f,0.f};
    for (int k = 0; k < H2; k += 32)
      acc = __builtin_amdgcn_mfma_f32_16x16x32_bf16(*(const bf16x8*)(A+k),
                                                    *(const bf16x8*)(B+k), acc, 0,0,0);
    #pragma unroll
    for (int r = 0; r < 4; r++){
      const int b_ = mt2*16 + quad*4 + r;
      pre[(b_*Tx + t)*Hx + nt2*16 + c16] = acc[r];
    }
  }
}

// ------- preout += [trg | states] @ Wp[:,0:768]^T  (adds onto ctx partial in pre) -----
__global__ void preout_gemm(const bf16_t* __restrict__ trgb, const float* __restrict__ states,
                            const bf16_t* __restrict__ Wpb, float* __restrict__ pre){
  const int gwid = (blockIdx.x*blockDim.x + threadIdx.x) >> 6;  // 0..32767
  const int lane = threadIdx.x & 63;
  const int quad = lane >> 4, c16 = lane & 15;
  const int mt = gwid >> 5, nt = gwid & 31;
  const int m = mt*16 + c16;
  const bf16_t* Bp = Wpb + (nt*16 + c16)*KP + quad*8;
  f32x4 acc = {0.f,0.f,0.f,0.f};
  const bf16_t* Ae = trgb + m*Ex + quad*8;
  for (int k = 0; k < Ex; k += 32)
    acc = __builtin_amdgcn_mfma_f32_16x16x32_bf16(*(const bf16x8*)(Ae+k),
                                                  *(const bf16x8*)(Bp+k), acc, 0,0,0);
  const float* As = states + m*Hx + quad*8;
  for (int k = 0; k < Hx; k += 32)
    acc = __builtin_amdgcn_mfma_f32_16x16x32_bf16(ld_cvt8(As+k),
                                                  *(const bf16x8*)(Bp+Ex+k), acc, 0,0,0);
  float* C = pre + mt*16*Hx + nt*16;
  #pragma unroll
  for (int r = 0; r < 4; r++){
    const int o = (quad*4 + r)*Hx + c16;
    C[o] = acc[r] + C[o];
  }
}

// ---------------- hidden (hT) + cell_state (zeros) ------------------------------------
__global__ void finalize_kernel(const float* __restrict__ hf,
                                float* __restrict__ hid, float* __restrict__ cell){
  const int i = blockIdx.x*256 + threadIdx.x;  // 0..65535
  hid[i]  = hf[i];
  cell[i] = 0.0f;
}

extern "C" void kernel_launch(void* const* d_in, const int* in_sizes, int n_in,
                              void* d_out, int out_size, void* d_ws, size_t ws_size,
                              hipStream_t stream){
  // --- input remap: find W_ih by its unique size (1536*1280); masks may be absent ---
  int shift = 0;
  for (int i = 0; i < n_in; i++){
    if (in_sizes[i] == 1966080){ shift = i - 8; break; }
  }
  #define IN(k) (((k) < 3) ? d_in[(k)] : d_in[(k) + shift])
  const float* trg = (const float*)IN(0);
  const float* eh  = (const float*)IN(1);
  const float* ef  = (const float*)IN(2);
  const float* Wk  = (const float*)IN(5);
  const float* Wq  = (const float*)IN(6);
  const float* ven = (const float*)IN(7);
  const float* Wih = (const float*)IN(8);
  const float* Whh = (const float*)IN(9);
  const float* bih = (const float*)IN(10);
  const float* bhh = (const float*)IN(11);
  const float* Wb  = (const float*)IN(12);
  const float* bb  = (const float*)IN(13);
  const float* Wp  = (const float*)IN(14);
  #undef IN

  // --- ws layout (bytes), total 35,848,192 (~34.2 MB) ---
  char* ws = (char*)d_ws;
  bf16_t* xbuf = (bf16_t*)(ws + 0);          //   327,680
  float*  hf   = (float* )(ws + 327680);     //   262,144
  bf16_t* hb   = (bf16_t*)(ws + 589824);     //   131,072
  float*  qf   = (float* )(ws + 720896);     //   262,144
  float*  ghf  = (float* )(ws + 983040);     //   786,432
  bf16_t* Wkb  = (bf16_t*)(ws + 1769472);    // 1,048,576
  bf16_t* Wqb  = (bf16_t*)(ws + 2818048);    //   524,288
  bf16_t* Whhb = (bf16_t*)(ws + 3342336);    // 1,572,864
  bf16_t* Wihb = (bf16_t*)(ws + 4915200);    // 3,932,160
  bf16_t* Wpb  = (bf16_t*)(ws + 8847360);    // 1,835,008
  bf16_t* trgb = (bf16_t*)(ws + 10682368);   // 8,388,608
  bf16_t* pk   = (bf16_t*)(ws + 19070976);   // 16,777,216

  float* out    = (float*)d_out;
  float* states = out + OUT_STATES;
  float* hid    = out + OUT_HID;
  float* pre    = out + OUT_PRE;
  float* cell   = out + OUT_CELL;

  // one-shot converts (fp32 -> bf16)
  cvt_kernel<<<dim3(512),  dim3(256), 0, stream>>>(Wk,  Wkb,  524288);
  cvt_kernel<<<dim3(256),  dim3(256), 0, stream>>>(Wq,  Wqb,  262144);
  cvt_kernel<<<dim3(768),  dim3(256), 0, stream>>>(Whh, Whhb, 786432);
  cvt_kernel<<<dim3(1920), dim3(256), 0, stream>>>(Wih, Wihb, 1966080);
  cvt_kernel<<<dim3(896),  dim3(256), 0, stream>>>(Wp,  Wpb,  917504);
  cvt_kernel<<<dim3(4096), dim3(256), 0, stream>>>(trg, trgb, 4194304);

  bridge_kernel<<<dim3(Bx), dim3(Hx), 0, stream>>>(ef, Wb, bb, hf, hb);
  pk_gemm<<<dim3(8192), dim3(256), 0, stream>>>(eh, Wkb, pk);

  for (int t = 0; t < Tx; t++){
    p1_kernel<<<dim3(256), dim3(256), 0, stream>>>(hb, Wqb, Whhb, qf, ghf);
    p2_kernel<<<dim3(256), dim3(256), 0, stream>>>(trg, eh, ven, pk, qf, xbuf, t);
    p3_kernel<<<dim3(128), dim3(256), 0, stream>>>(Wihb, bih, bhh, Wpb, xbuf, ghf,
                                                   hf, hb, states, pre, t);
  }

  preout_gemm<<<dim3(8192), dim3(256), 0, stream>>>(trgb, states, Wpb, pre);
  finalize_kernel<<<dim3(256), dim3(256), 0, stream>>>(hf, hid, cell);
}